// Round 4
// baseline (134.796 us; speedup 1.0000x reference)
//
#include <hip/hip_runtime.h>

#define BIG 1e8f
#define LN2 0.69314718f
#define LOG2E 1.44269504f
#define M2L -2.8853900818f  /* -2*log2(e) */

#define RSLOT 112           /* band ring slots (anti-diagonal rows) */
#define DRB 1040            /* drow stride bytes: 256 cols * 4B(half2) + 16 pad */

/* dynamic LDS layout */
#define OFF_XH   116480     /* band: [0, 116480) = 112*1040 */
#define OFF_X2S  132864     /* xh: 16384 B f16 */
#define OFF_Y2S  133888
#define OFF_RDY  134912     /* 16 ready flags */
#define OFF_PRG  134976     /* consumer progress */
#define LDS_BYTES 135040

typedef _Float16 half8 __attribute__((ext_vector_type(8)));
typedef _Float16 half2_t __attribute__((ext_vector_type(2)));
typedef float f32x4 __attribute__((ext_vector_type(4)));

__device__ __forceinline__ float exp2g(float x) {
#if __has_builtin(__builtin_amdgcn_exp2f)
    return __builtin_amdgcn_exp2f(x);
#else
    return exp2f(x);
#endif
}
__device__ __forceinline__ float log2g(float x) {
#if __has_builtin(__builtin_amdgcn_logf)
    return __builtin_amdgcn_logf(x);
#else
    return log2f(x);
#endif
}

// pack two f32 to f16x2 (v_cvt_pkrtz_f16_f32)
__device__ __forceinline__ half2_t pkrtz(float a, float b) {
    return __builtin_bit_cast(half2_t, __builtin_amdgcn_cvt_pkrtz(a, b));
}

// whole-wave shift-up-by-1 via DPP wave_shr:1; lane 0 receives oldv.
__device__ __forceinline__ float shfl_up1(float v, float oldv) {
    int r = __builtin_amdgcn_update_dpp(
        __builtin_bit_cast(int, oldv), __builtin_bit_cast(int, v),
        0x138 /*wave_shr:1*/, 0xf, 0xf, false);
    return __builtin_bit_cast(float, r);
}

__device__ __forceinline__ void dec2(unsigned int w, float& a, float& b) {
    half2_t h = __builtin_bit_cast(half2_t, w);
    a = (float)h[0];
    b = (float)h[1];
}

// Inactive-lane word masks: per-column-DISTINCT huge f16 values (see R2).
#define MASKW0 0x7BFF7BFFu  /* 65504 */
#define MASKW1 0x70007000u  /* 8192  */
#define MASKW2 0x60006000u  /* 512   */
#define MASKW3 0x50005000u  /* 32    */

// One block = one batch, 2 waves on 2 SIMDs.
// Wave 1 (producer): MFMA-computes dist*log2(e) as f16 (dA,dB) pairs into an
//   anti-diagonal-major LDS ring. Unchanged.
// Wave 0 (consumer): DP wavefront in exponential-pair form (M,S):
//   v = M - log2(S). SELECTLESS merges: So = Sa*2^(mu-Ma) + Sb*2^(mu-Mb)
//   with mu = min(Ma,Mb) — one exponent is exactly 0, so math is identical
//   to the cmp/cndmask form but with ZERO VCC pressure. Superstep is split
//   into M-phase (pure min/add/sub spine) / exp block (32 independent
//   v_exp_f32) / S-phase (mul+fma), giving the in-order scheduler freedom.
__global__ __launch_bounds__(128, 1) void sdtw_kernel(
    const float* __restrict__ x, const float* __restrict__ y,
    float* __restrict__ out) {
    extern __shared__ __align__(16) char smem[];
    unsigned char* band = (unsigned char*)smem;
    _Float16* xh = (_Float16*)(smem + OFF_XH);
    float* x2sL = (float*)(smem + OFF_X2S);   // row norms * log2(e)
    float* y2sL = (float*)(smem + OFF_Y2S);
    volatile int* rdy = (volatile int*)(smem + OFF_RDY);
    volatile int* prg = (volatile int*)(smem + OFF_PRG);

    const int tid = threadIdx.x;  // 0..127
    const int b = blockIdx.x;
    const float* xb = x + (size_t)b * 8192;
    const float* yb = y + (size_t)b * 8192;

    // ---- phase 0 (both waves): stage x as f16 + scaled norms; flags ----
#pragma unroll
    for (int rr = 0; rr < 2; rr++) {
        const int r = tid + rr * 128;
        const float4* px = (const float4*)(xb + r * 32);
        union { _Float16 h[32]; half8 v[4]; } uc;
        float s2 = 0.f;
#pragma unroll
        for (int q = 0; q < 8; q++) {
            float4 f = px[q];
            s2 += f.x * f.x + f.y * f.y + f.z * f.z + f.w * f.w;
            uc.h[4 * q + 0] = (_Float16)f.x;
            uc.h[4 * q + 1] = (_Float16)f.y;
            uc.h[4 * q + 2] = (_Float16)f.z;
            uc.h[4 * q + 3] = (_Float16)f.w;
        }
        half8* dst = (half8*)&xh[r * 32];
#pragma unroll
        for (int q = 0; q < 4; q++) dst[q] = uc.v[q];
        x2sL[r] = s2 * LOG2E;

        const float4* py = (const float4*)(yb + r * 32);
        float t2 = 0.f;
#pragma unroll
        for (int q = 0; q < 8; q++) {
            float4 f = py[q];
            t2 += f.x * f.x + f.y * f.y + f.z * f.z + f.w * f.w;
        }
        y2sL[r] = t2 * LOG2E;
    }
    if (tid < 16) rdy[tid] = 0;
    if (tid == 16) *prg = 0;
    __syncthreads();

    if (tid >= 64) {
        // ================= producer wave =================
        const int lane = tid - 64;
        const int qd = lane >> 4, xr = lane & 15;

        half8 yfrag[16];  // B-frags: lane holds y[ci*16+xr][qd*8+j]
        float yvL[16];
#pragma unroll
        for (int ci = 0; ci < 16; ci++) {
            const float* yp = yb + (ci * 16 + xr) * 32 + qd * 8;
            float4 f0 = *(const float4*)yp;
            float4 f1 = *(const float4*)(yp + 4);
            half8 v;
            v[0] = (_Float16)f0.x; v[1] = (_Float16)f0.y;
            v[2] = (_Float16)f0.z; v[3] = (_Float16)f0.w;
            v[4] = (_Float16)f1.x; v[5] = (_Float16)f1.y;
            v[6] = (_Float16)f1.z; v[7] = (_Float16)f1.w;
            yfrag[ci] = v;
            yvL[ci] = y2sL[ci * 16 + xr];
        }

        for (int sg = 0; sg < 16; sg++) {
            // ring-reuse gate: stripe sg touches drows [8sg, 8sg+70]; the
            // aliased drows (d-112) need consumer progress >= 8sg-40.
            if (sg >= 6) {
                const int need = 8 * sg - 40;
                while (*prg < need) {}
            }
            const half8 xf = *(const half8*)&xh[(sg * 16 + xr) * 32 + qd * 8];
            const float4 xl = *(const float4*)&x2sL[sg * 16 + qd * 4];
            const int p0 = 8 * sg + 2 * qd;  // global pair of acc[0],acc[1]
#pragma unroll
            for (int ci = 0; ci < 16; ci++) {
                f32x4 acc = {0.f, 0.f, 0.f, 0.f};
                acc = __builtin_amdgcn_mfma_f32_16x16x32_f16(xf, yfrag[ci], acc, 0, 0, 0);
                const int c = ci * 16 + xr;
                const float yv = yvL[ci];
                const float d0 = fmaxf(fmaf(M2L, acc[0], xl.x + yv), 0.f);
                const float d1 = fmaxf(fmaf(M2L, acc[1], xl.y + yv), 0.f);
                const float d2 = fmaxf(fmaf(M2L, acc[2], xl.z + yv), 0.f);
                const float d3 = fmaxf(fmaf(M2L, acc[3], xl.w + yv), 0.f);
                const half2_t h01 = pkrtz(d0, d1);
                const half2_t h23 = pkrtz(d2, d3);
                const int dr0 = p0 + (c >> 2);          // anti-diagonal row
                int s0_ = dr0;     if (s0_ >= RSLOT) s0_ -= RSLOT;
                int s1_ = dr0 + 1; if (s1_ >= RSLOT) s1_ -= RSLOT;
                *(half2_t*)&band[s0_ * DRB + 4 * c] = h01;
                *(half2_t*)&band[s1_ * DRB + 4 * c] = h23;
            }
            __threadfence_block();  // drain LDS writes before flagging
            if (lane == 0) rdy[sg] = 1;
        }
        return;
    }

    // ================= consumer (DP) wave =================
    const int lane = tid;
    // relay state in pair form (unconditional commits; masking is on inputs)
    float MpA3 = BIG, SpA3 = 1.f, MpB3 = BIG, SpB3 = 1.f;
    // A-row softmin pairs (up,diag) for the upcoming superstep
    float Mm[4], Sm[4];
    Mm[0] = (lane == 0) ? 0.f : BIG;
    Sm[0] = (lane == 0) ? 1.f : 2.f;
    Mm[1] = BIG; Sm[1] = 2.f;
    Mm[2] = BIG; Sm[2] = 2.f;
    Mm[3] = BIG; Sm[3] = 2.f;

    while (rdy[0] == 0) {}
    uint4 wreg = *(const uint4*)&band[16 * lane];  // drow 0

    auto step = [&](int s_) {
        // relays (DPP), independent
        const float MLA = shfl_up1(MpA3, BIG);
        const float MLB = shfl_up1(MpB3, BIG);
        const float SLA = shfl_up1(SpA3, 1.f);
        const float SLB = shfl_up1(SpB3, 1.f);

        // input masking: inactive lanes get huge, per-column-distinct d's
        const bool act = (unsigned)(s_ - lane - 1) < 128u;
        const unsigned wx = act ? wreg.x : MASKW0;
        const unsigned wy = act ? wreg.y : MASKW1;
        const unsigned wz = act ? wreg.z : MASKW2;
        const unsigned ww = act ? wreg.w : MASKW3;
        float dA[4], dB[4];
        dec2(wx, dA[0], dB[0]);
        dec2(wy, dA[1], dB[1]);
        dec2(wz, dA[2], dB[2]);
        dec2(ww, dA[3], dB[3]);

        // prefetch next drow (= s_), used next superstep — issued early
        int dn = (s_ > 190) ? 190 : s_;
        if (dn >= RSLOT) dn -= RSLOT;
        const uint4 wnext = *(const uint4*)&band[dn * DRB + 16 * lane];

        // ---- M phase: pure min/add/sub (the only true serial spine) ----
        float MA[4], xAm[4], xAv[4];
        float prevA = MLA;
#pragma unroll
        for (int k = 0; k < 4; k++) {
            const float mu = fminf(Mm[k], prevA);
            xAm[k] = mu - Mm[k];
            xAv[k] = mu - prevA;
            MA[k] = dA[k] + mu;
            prevA = MA[k];
        }
        float muN[4], xNa[4], xNb[4];
        float diagA = MLA;
#pragma unroll
        for (int k = 0; k < 4; k++) {
            muN[k] = fminf(MA[k], diagA);
            xNa[k] = muN[k] - MA[k];
            xNb[k] = muN[k] - diagA;
            diagA = MA[k];
        }
        float MB[4], xBm[4], xBv[4];
        float prevB = MLB;
#pragma unroll
        for (int k = 0; k < 4; k++) {
            const float mu = fminf(muN[k], prevB);
            xBm[k] = mu - muN[k];
            xBv[k] = mu - prevB;
            MB[k] = dB[k] + mu;
            prevB = MB[k];
        }
        float muC[4], xCa[4], xCb[4];
        float diagB = MLB;
#pragma unroll
        for (int k = 0; k < 4; k++) {
            muC[k] = fminf(MB[k], diagB);
            xCa[k] = muC[k] - MB[k];
            xCb[k] = muC[k] - diagB;
            diagB = MB[k];
        }

        // ---- exp block: 32 independent v_exp_f32 ----
        float eAm[4], eAv[4], eNa[4], eNb[4], eBm[4], eBv[4], eCa[4], eCb[4];
#pragma unroll
        for (int k = 0; k < 4; k++) {
            eAm[k] = exp2g(xAm[k]);
            eAv[k] = exp2g(xAv[k]);
            eNa[k] = exp2g(xNa[k]);
            eNb[k] = exp2g(xNb[k]);
            eBm[k] = exp2g(xBm[k]);
            eBv[k] = exp2g(xBv[k]);
            eCa[k] = exp2g(xCa[k]);
            eCb[k] = exp2g(xCb[k]);
        }

        // ---- S phase: mul+fma chains (nothing downstream this superstep) ----
        float SA[4];
        float ps = SLA;
#pragma unroll
        for (int k = 0; k < 4; k++) {
            SA[k] = fmaf(Sm[k], eAm[k], ps * eAv[k]);
            ps = SA[k];
        }
        float SN[4];
        float dsg = SLA;
#pragma unroll
        for (int k = 0; k < 4; k++) {
            SN[k] = fmaf(SA[k], eNa[k], dsg * eNb[k]);
            dsg = SA[k];
        }
        float SB[4];
        ps = SLB;
#pragma unroll
        for (int k = 0; k < 4; k++) {
            SB[k] = fmaf(SN[k], eBm[k], ps * eBv[k]);
            ps = SB[k];
        }
        dsg = SLB;
#pragma unroll
        for (int k = 0; k < 4; k++) {
            Sm[k] = fmaf(SB[k], eCa[k], dsg * eCb[k]);
            dsg = SB[k];
        }

        // UNCONDITIONAL commit (input masking makes inactive lanes no-ops)
        MpA3 = MA[3]; SpA3 = SA[3];
        MpB3 = MB[3]; SpB3 = SB[3];
#pragma unroll
        for (int k = 0; k < 4; k++) Mm[k] = muC[k];
        wreg = wnext;
    };

    // prologue: supersteps 1..7 (stripe 0 covers drows 0..7)
#pragma unroll
    for (int s_ = 1; s_ < 8; s_++) step(s_);

    // 23 groups of 8 supersteps, poll/publish hoisted to group head
    for (int g = 1; g < 24; g++) {
        int st = (g > 15) ? 15 : g;
        while (rdy[st] == 0) {}
        if (lane == 0) *prg = 8 * g;
        const int s0 = 8 * g;
#pragma unroll
        for (int k = 0; k < 8; k++) step(s0 + k);
    }

    // lane 63's superstep-191 commit is the final cell D[256][256]
    if (lane == 63)
        atomicAdd(out, (MpB3 - log2g(SpB3)) * (LN2 / 256.f));
}

extern "C" void kernel_launch(void* const* d_in, const int* in_sizes, int n_in,
                              void* d_out, int out_size, void* d_ws, size_t ws_size,
                              hipStream_t stream) {
    const float* x = (const float*)d_in[0];
    const float* y = (const float*)d_in[1];
    float* out = (float*)d_out;
    const int B = in_sizes[0] / (256 * 32);  // 256

    (void)hipFuncSetAttribute((const void*)sdtw_kernel,
                              hipFuncAttributeMaxDynamicSharedMemorySize,
                              LDS_BYTES);
    (void)hipMemsetAsync(d_out, 0, sizeof(float), stream);
    sdtw_kernel<<<dim3(B), dim3(128), LDS_BYTES, stream>>>(x, y, out);
}

// Round 5
// 130.273 us; speedup vs baseline: 1.0347x; 1.0347x over previous
//
#include <hip/hip_runtime.h>

#define BIG 1e8f
#define LN2 0.69314718f
#define LOG2E 1.44269504f
#define M2L -2.8853900818f  /* -2*log2(e) */

#define RSLOT 104           /* band ring slots (anti-diagonal rows) */
#define DRB 1040            /* drow stride bytes: 256 cols * 4B(half2) + 16 pad */

/* dynamic LDS layout */
#define OFF_XH    108160    /* band: [0, 108160) = 104*1040 */
#define OFF_X2S   124544    /* xh: 16384 B f16 */
#define OFF_Y2S   125568
#define OFF_DR    126592    /* delta ring: 8 slots * 4096 B = 32768 */
#define OFF_RDY   159360    /* 16 ready flags */
#define OFF_PRG   159424    /* consumer(M) progress for producer gate */
#define OFF_MPRG  159428    /* M-wave superstep progress (for S) */
#define OFF_SPRG  159432    /* S-wave superstep progress (for M ring reuse) */
#define OFF_MDONE 159436
#define OFF_MVAL  159440
#define LDS_BYTES 159456

typedef _Float16 half8 __attribute__((ext_vector_type(8)));
typedef _Float16 half2_t __attribute__((ext_vector_type(2)));
typedef float f32x4 __attribute__((ext_vector_type(4)));

__device__ __forceinline__ float exp2g(float x) {
#if __has_builtin(__builtin_amdgcn_exp2f)
    return __builtin_amdgcn_exp2f(x);
#else
    return exp2f(x);
#endif
}
__device__ __forceinline__ float log2g(float x) {
#if __has_builtin(__builtin_amdgcn_logf)
    return __builtin_amdgcn_logf(x);
#else
    return log2f(x);
#endif
}

__device__ __forceinline__ half2_t pkrtz(float a, float b) {
    return __builtin_bit_cast(half2_t, __builtin_amdgcn_cvt_pkrtz(a, b));
}

// whole-wave shift-up-by-1 via DPP wave_shr:1; lane 0 receives oldv.
__device__ __forceinline__ float shfl_up1(float v, float oldv) {
    int r = __builtin_amdgcn_update_dpp(
        __builtin_bit_cast(int, oldv), __builtin_bit_cast(int, v),
        0x138 /*wave_shr:1*/, 0xf, 0xf, false);
    return __builtin_bit_cast(float, r);
}

__device__ __forceinline__ void dec2(unsigned int w, float& a, float& b) {
    half2_t h = __builtin_bit_cast(half2_t, w);
    a = (float)h[0];
    b = (float)h[1];
}

// Inactive-lane word masks: per-column-DISTINCT huge f16 values (see R2).
#define MASKW0 0x7BFF7BFFu  /* 65504 */
#define MASKW1 0x70007000u  /* 8192  */
#define MASKW2 0x60006000u  /* 512   */
#define MASKW3 0x50005000u  /* 32    */

// One block = one batch, 3 waves on 3 SIMDs.
// Wave P (tid 128..191): MFMA dist producer into anti-diagonal LDS band ring.
// Wave M (tid  0.. 63): tropical (min-plus) DP spine. In pair form
//   v = M - log2(S), the M-recurrence never depends on S. M computes all
//   min/add chains and ships the 16 per-superstep merge deltas
//   (delta = M1 - M2, f32, bit-exact) to an 8-slot LDS ring.
// Wave S (tid 64..127): consumes deltas, computes the exp2/select-fma
//   S-chains (identical algebra to the previously-verified unified kernel),
//   relays S across lanes with its own DPP, emits the final result.
// M->S gating in pairs of supersteps; S->M ring-reuse gate (slack 7).
__global__ __launch_bounds__(192, 1) void sdtw_kernel(
    const float* __restrict__ x, const float* __restrict__ y,
    float* __restrict__ out) {
    extern __shared__ __align__(16) char smem[];
    unsigned char* band = (unsigned char*)smem;
    _Float16* xh = (_Float16*)(smem + OFF_XH);
    float* x2sL = (float*)(smem + OFF_X2S);   // row norms * log2(e)
    float* y2sL = (float*)(smem + OFF_Y2S);
    volatile int* rdy = (volatile int*)(smem + OFF_RDY);
    volatile int* prg = (volatile int*)(smem + OFF_PRG);
    volatile int* mprg = (volatile int*)(smem + OFF_MPRG);
    volatile int* sprg = (volatile int*)(smem + OFF_SPRG);
    volatile int* mdone = (volatile int*)(smem + OFF_MDONE);
    volatile float* mval = (volatile float*)(smem + OFF_MVAL);

    const int tid = threadIdx.x;  // 0..191
    const int b = blockIdx.x;
    const float* xb = x + (size_t)b * 8192;
    const float* yb = y + (size_t)b * 8192;

    // ---- phase 0 (waves M,S): stage x as f16 + scaled norms ----
    if (tid < 128) {
#pragma unroll
        for (int rr = 0; rr < 2; rr++) {
            const int r = tid + rr * 128;
            const float4* px = (const float4*)(xb + r * 32);
            union { _Float16 h[32]; half8 v[4]; } uc;
            float s2 = 0.f;
#pragma unroll
            for (int q = 0; q < 8; q++) {
                float4 f = px[q];
                s2 += f.x * f.x + f.y * f.y + f.z * f.z + f.w * f.w;
                uc.h[4 * q + 0] = (_Float16)f.x;
                uc.h[4 * q + 1] = (_Float16)f.y;
                uc.h[4 * q + 2] = (_Float16)f.z;
                uc.h[4 * q + 3] = (_Float16)f.w;
            }
            half8* dst = (half8*)&xh[r * 32];
#pragma unroll
            for (int q = 0; q < 4; q++) dst[q] = uc.v[q];
            x2sL[r] = s2 * LOG2E;

            const float4* py = (const float4*)(yb + r * 32);
            float t2 = 0.f;
#pragma unroll
            for (int q = 0; q < 8; q++) {
                float4 f = py[q];
                t2 += f.x * f.x + f.y * f.y + f.z * f.z + f.w * f.w;
            }
            y2sL[r] = t2 * LOG2E;
        }
    }
    if (tid < 16) rdy[tid] = 0;
    if (tid == 16) *prg = 0;
    if (tid == 17) *mprg = 0;
    if (tid == 18) *sprg = 0;
    if (tid == 19) *mdone = 0;
    __syncthreads();

    if (tid >= 128) {
        // ================= producer wave =================
        const int lane = tid - 128;
        const int qd = lane >> 4, xr = lane & 15;

        half8 yfrag[16];  // B-frags: lane holds y[ci*16+xr][qd*8+j]
        float yvL[16];
#pragma unroll
        for (int ci = 0; ci < 16; ci++) {
            const float* yp = yb + (ci * 16 + xr) * 32 + qd * 8;
            float4 f0 = *(const float4*)yp;
            float4 f1 = *(const float4*)(yp + 4);
            half8 v;
            v[0] = (_Float16)f0.x; v[1] = (_Float16)f0.y;
            v[2] = (_Float16)f0.z; v[3] = (_Float16)f0.w;
            v[4] = (_Float16)f1.x; v[5] = (_Float16)f1.y;
            v[6] = (_Float16)f1.z; v[7] = (_Float16)f1.w;
            yfrag[ci] = v;
            yvL[ci] = y2sL[ci * 16 + xr];
        }

        for (int sg = 0; sg < 16; sg++) {
            // ring-reuse gate (RSLOT=104): stripe sg writes drows <= 8sg+70,
            // overwriting drow d-104; safe when M completed superstep d-104,
            // i.e. prg >= 8sg-33; use -32 (+1 margin, same as proven -40/112).
            if (sg >= 5) {
                const int need = 8 * sg - 32;
                while (*prg < need) {}
            }
            const half8 xf = *(const half8*)&xh[(sg * 16 + xr) * 32 + qd * 8];
            const float4 xl = *(const float4*)&x2sL[sg * 16 + qd * 4];
            const int p0 = 8 * sg + 2 * qd;  // global pair of acc[0],acc[1]
#pragma unroll
            for (int ci = 0; ci < 16; ci++) {
                f32x4 acc = {0.f, 0.f, 0.f, 0.f};
                acc = __builtin_amdgcn_mfma_f32_16x16x32_f16(xf, yfrag[ci], acc, 0, 0, 0);
                const int c = ci * 16 + xr;
                const float yv = yvL[ci];
                const float d0 = fmaxf(fmaf(M2L, acc[0], xl.x + yv), 0.f);
                const float d1 = fmaxf(fmaf(M2L, acc[1], xl.y + yv), 0.f);
                const float d2 = fmaxf(fmaf(M2L, acc[2], xl.z + yv), 0.f);
                const float d3 = fmaxf(fmaf(M2L, acc[3], xl.w + yv), 0.f);
                const half2_t h01 = pkrtz(d0, d1);
                const half2_t h23 = pkrtz(d2, d3);
                const int dr0 = p0 + (c >> 2);          // anti-diagonal row
                int s0_ = dr0;     if (s0_ >= RSLOT) s0_ -= RSLOT;
                int s1_ = dr0 + 1; if (s1_ >= RSLOT) s1_ -= RSLOT;
                *(half2_t*)&band[s0_ * DRB + 4 * c] = h01;
                *(half2_t*)&band[s1_ * DRB + 4 * c] = h23;
            }
            __threadfence_block();  // drain LDS writes before flagging
            if (lane == 0) rdy[sg] = 1;
        }
        return;
    }

    if (tid < 64) {
        // ================= M-wave (tropical spine) =================
        const int lane = tid;
        float MpA3 = BIG, MpB3 = BIG;
        float Mm[4];
        Mm[0] = (lane == 0) ? 0.f : BIG;
        Mm[1] = BIG; Mm[2] = BIG; Mm[3] = BIG;
        char* dbase = (char*)smem + OFF_DR + lane * 16;

        while (rdy[0] == 0) {}
        uint4 wreg = *(const uint4*)&band[16 * lane];  // drow 0

        auto mstep = [&](int s_) {
            const float MLA = shfl_up1(MpA3, BIG);
            const float MLB = shfl_up1(MpB3, BIG);

            const bool act = (unsigned)(s_ - lane - 1) < 128u;
            const unsigned wx = act ? wreg.x : MASKW0;
            const unsigned wy = act ? wreg.y : MASKW1;
            const unsigned wz = act ? wreg.z : MASKW2;
            const unsigned ww = act ? wreg.w : MASKW3;
            float dA[4], dB[4];
            dec2(wx, dA[0], dB[0]);
            dec2(wy, dA[1], dB[1]);
            dec2(wz, dA[2], dB[2]);
            dec2(ww, dA[3], dB[3]);

            // prefetch next drow (= s_), used next superstep
            int dn = (s_ > 190) ? 190 : s_;
            if (dn >= RSLOT) dn -= RSLOT;
            const uint4 wnext = *(const uint4*)&band[dn * DRB + 16 * lane];

            f32x4 gA, gN, gB, gC;  // shipped deltas (M1 - M2 convention)
            float MA[4];
            float prevA = MLA;
#pragma unroll
            for (int k = 0; k < 4; k++) {
                gA[k] = Mm[k] - prevA;
                const float mu = fminf(Mm[k], prevA);
                MA[k] = dA[k] + mu;
                prevA = MA[k];
            }
            float muN[4];
            float diagA = MLA;
#pragma unroll
            for (int k = 0; k < 4; k++) {
                gN[k] = MA[k] - diagA;
                muN[k] = fminf(MA[k], diagA);
                diagA = MA[k];
            }
            float MB[4];
            float prevB = MLB;
#pragma unroll
            for (int k = 0; k < 4; k++) {
                gB[k] = muN[k] - prevB;
                const float mu = fminf(muN[k], prevB);
                MB[k] = dB[k] + mu;
                prevB = MB[k];
            }
            float diagB = MLB;
#pragma unroll
            for (int k = 0; k < 4; k++) {
                gC[k] = MB[k] - diagB;
                Mm[k] = fminf(MB[k], diagB);
                diagB = MB[k];
            }

            char* dp = dbase + (s_ & 7) * 4096;
            *(f32x4*)(dp)        = gA;
            *(f32x4*)(dp + 1024) = gN;
            *(f32x4*)(dp + 2048) = gB;
            *(f32x4*)(dp + 3072) = gC;

            MpA3 = MA[3]; MpB3 = MB[3];
            wreg = wnext;
        };

        auto mpair = [&](int s_) {
            // ring-8 reuse gate: writes slots s_,s_+1 overwrite data of
            // supersteps s_-8,s_-7; S must have consumed through s_-7.
            while (*sprg < s_ - 7) {}
            mstep(s_); mstep(s_ + 1);
            __threadfence_block();
            if (lane == 0) *mprg = s_ + 1;
        };

        // prologue: supersteps 1..7
        mstep(1);
        __threadfence_block();
        if (lane == 0) *mprg = 1;
        mpair(2); mpair(4); mpair(6);

        // 23 groups of 8 supersteps, band poll / prg publish at head
        for (int g = 1; g < 24; g++) {
            int st = (g > 15) ? 15 : g;
            while (rdy[st] == 0) {}
            if (lane == 0) *prg = 8 * g;
            const int s0 = 8 * g;
            mpair(s0); mpair(s0 + 2); mpair(s0 + 4); mpair(s0 + 6);
        }

        if (lane == 63) *mval = MpB3;
        __threadfence_block();
        if (lane == 0) *mdone = 1;
        return;
    }

    // ================= S-wave (soft correction chains) =================
    {
        const int lane = tid - 64;
        float SpA3 = 1.f, SpB3 = 1.f;
        float Sm[4];
        Sm[0] = (lane == 0) ? 1.f : 2.f;
        Sm[1] = 2.f; Sm[2] = 2.f; Sm[3] = 2.f;
        const char* dbase = (const char*)smem + OFF_DR + lane * 16;

        while (*mprg < 3) {}
        f32x4 cA = *(const f32x4*)(dbase + (1 & 7) * 4096);
        f32x4 cN = *(const f32x4*)(dbase + (1 & 7) * 4096 + 1024);
        f32x4 cB = *(const f32x4*)(dbase + (1 & 7) * 4096 + 2048);
        f32x4 cC = *(const f32x4*)(dbase + (1 & 7) * 4096 + 3072);

        auto sstep = [&](int s_) {
            // prefetch next slot (gated: pair-head ensures mprg >= s_+1)
            const int sn = (s_ >= 191) ? 191 : s_ + 1;
            const char* np = dbase + (sn & 7) * 4096;
            const f32x4 nA = *(const f32x4*)(np);
            const f32x4 nN = *(const f32x4*)(np + 1024);
            const f32x4 nB = *(const f32x4*)(np + 2048);
            const f32x4 nC = *(const f32x4*)(np + 3072);

            const float SLA = shfl_up1(SpA3, 1.f);
            const float SLB = shfl_up1(SpB3, 1.f);

            // convention: delta<=0 -> fma(S2,e,S1), else fma(S1,e,S2)
            float SA[4];
            float ps = SLA;
#pragma unroll
            for (int k = 0; k < 4; k++) {
                const float e = exp2g(-fabsf(cA[k]));
                SA[k] = (cA[k] <= 0.f) ? fmaf(ps, e, Sm[k]) : fmaf(Sm[k], e, ps);
                ps = SA[k];
            }
            float SN[4];
            float dsg = SLA;
#pragma unroll
            for (int k = 0; k < 4; k++) {
                const float e = exp2g(-fabsf(cN[k]));
                SN[k] = (cN[k] <= 0.f) ? fmaf(dsg, e, SA[k]) : fmaf(SA[k], e, dsg);
                dsg = SA[k];
            }
            float SB[4];
            ps = SLB;
#pragma unroll
            for (int k = 0; k < 4; k++) {
                const float e = exp2g(-fabsf(cB[k]));
                SB[k] = (cB[k] <= 0.f) ? fmaf(ps, e, SN[k]) : fmaf(SN[k], e, ps);
                ps = SB[k];
            }
            dsg = SLB;
#pragma unroll
            for (int k = 0; k < 4; k++) {
                const float e = exp2g(-fabsf(cC[k]));
                Sm[k] = (cC[k] <= 0.f) ? fmaf(dsg, e, SB[k]) : fmaf(SB[k], e, dsg);
                dsg = SB[k];
            }
            SpA3 = SA[3]; SpB3 = SB[3];
            cA = nA; cN = nN; cB = nB; cC = nC;
        };

        for (int u0 = 1; u0 <= 189; u0 += 2) {
            while (*mprg < u0 + 2) {}  // covers reads issued up to u0+2
            sstep(u0); sstep(u0 + 1);
            if (lane == 0) *sprg = u0 + 1;
        }
        while (*mprg < 191) {}
        sstep(191);

        while (*mdone == 0) {}
        if (lane == 63)
            atomicAdd(out, ((*mval) - log2g(SpB3)) * (LN2 / 256.f));
    }
}

extern "C" void kernel_launch(void* const* d_in, const int* in_sizes, int n_in,
                              void* d_out, int out_size, void* d_ws, size_t ws_size,
                              hipStream_t stream) {
    const float* x = (const float*)d_in[0];
    const float* y = (const float*)d_in[1];
    float* out = (float*)d_out;
    const int B = in_sizes[0] / (256 * 32);  // 256

    (void)hipFuncSetAttribute((const void*)sdtw_kernel,
                              hipFuncAttributeMaxDynamicSharedMemorySize,
                              LDS_BYTES);
    (void)hipMemsetAsync(d_out, 0, sizeof(float), stream);
    sdtw_kernel<<<dim3(B), dim3(192), LDS_BYTES, stream>>>(x, y, out);
}

// Round 7
// 120.982 us; speedup vs baseline: 1.1142x; 1.0768x over previous
//
#include <hip/hip_runtime.h>

#define BIG 1e8f
#define LN2 0.69314718f
#define LOG2E 1.44269504f
#define M2L -2.8853900818f  /* -2*log2(e) */

#define RSLOT 112           /* band ring slots (anti-diagonal rows) */
#define DRB 1040            /* drow stride bytes: 256 cols * 4B(half2) + 16 pad */

/* dynamic LDS layout */
#define OFF_XH   116480     /* band: [0, 116480) = 112*1040 */
#define OFF_X2S  132864     /* xh: 16384 B f16 */
#define OFF_Y2S  133888
#define OFF_RDY  134912     /* 16 ready flags */
#define OFF_PRG  134976     /* consumer progress */
#define LDS_BYTES 135040

typedef _Float16 half8 __attribute__((ext_vector_type(8)));
typedef _Float16 half2_t __attribute__((ext_vector_type(2)));
typedef float f32x4 __attribute__((ext_vector_type(4)));

__device__ __forceinline__ float exp2g(float x) {
#if __has_builtin(__builtin_amdgcn_exp2f)
    return __builtin_amdgcn_exp2f(x);
#else
    return exp2f(x);
#endif
}
__device__ __forceinline__ float log2g(float x) {
#if __has_builtin(__builtin_amdgcn_logf)
    return __builtin_amdgcn_logf(x);
#else
    return log2f(x);
#endif
}

__device__ __forceinline__ half2_t pkrtz(float a, float b) {
    return __builtin_bit_cast(half2_t, __builtin_amdgcn_cvt_pkrtz(a, b));
}

// whole-wave shift-up-by-1 via DPP wave_shr:1; lane 0 receives oldv.
__device__ __forceinline__ float shfl_up1(float v, float oldv) {
    int r = __builtin_amdgcn_update_dpp(
        __builtin_bit_cast(int, oldv), __builtin_bit_cast(int, v),
        0x138 /*wave_shr:1*/, 0xf, 0xf, false);
    return __builtin_bit_cast(float, r);
}

__device__ __forceinline__ void dec2(unsigned int w, float& a, float& b) {
    half2_t h = __builtin_bit_cast(half2_t, w);
    a = (float)h[0];
    b = (float)h[1];
}

// SELECTLESS 3-way softmin cell in exponential-pair form (v = M - log2(S)):
// out = d + softmin{up, diag, left}. mu = min3 -> one exponent is exactly 0
// (exp2(0)=1), the far ones flush to exact 0 -- no cmp/cndmask machinery.
// 11 ops/cell vs 16 for the two-stage 2-way-merge form.
__device__ __forceinline__ void cell3(float Mu, float Su, float Mg, float Sg,
                                      float Ml, float Sl, float dd,
                                      float& Mo, float& So) {
    const float mu = fminf(fminf(Mu, Mg), Ml);   // v_min3_f32
    const float eu = exp2g(mu - Mu);
    const float eg = exp2g(mu - Mg);
    const float el = exp2g(mu - Ml);
    So = fmaf(Su, eu, fmaf(Sg, eg, Sl * el));
    Mo = dd + mu;
}

// Inactive-lane word masks: per-column-DISTINCT huge f16 values (see R2).
#define MASKW0 0x7BFF7BFFu  /* 65504 */
#define MASKW1 0x70007000u  /* 8192  */
#define MASKW2 0x60006000u  /* 512   */
#define MASKW3 0x50005000u  /* 32    */

// One block = one batch, 2 waves on 2 SIMDs.
// Wave 1 (producer): MFMA-computes dist*log2(e) as f16 (dA,dB) pairs into an
//   anti-diagonal-major LDS ring. Unchanged (proven).
// Wave 0 (consumer): DP wavefront, 8 cells/superstep, each a single 3-way
//   pair-softmin (cell3). Unconditional commits via input masking.
__global__ __launch_bounds__(128, 1) void sdtw_kernel(
    const float* __restrict__ x, const float* __restrict__ y,
    float* __restrict__ out) {
    extern __shared__ __align__(16) char smem[];
    unsigned char* band = (unsigned char*)smem;
    _Float16* xh = (_Float16*)(smem + OFF_XH);
    float* x2sL = (float*)(smem + OFF_X2S);   // row norms * log2(e)
    float* y2sL = (float*)(smem + OFF_Y2S);
    volatile int* rdy = (volatile int*)(smem + OFF_RDY);
    volatile int* prg = (volatile int*)(smem + OFF_PRG);

    const int tid = threadIdx.x;  // 0..127
    const int b = blockIdx.x;
    const float* xb = x + (size_t)b * 8192;
    const float* yb = y + (size_t)b * 8192;

    // ---- phase 0 (both waves): stage x as f16 + scaled norms; flags ----
#pragma unroll
    for (int rr = 0; rr < 2; rr++) {
        const int r = tid + rr * 128;
        const float4* px = (const float4*)(xb + r * 32);
        union { _Float16 h[32]; half8 v[4]; } uc;
        float s2 = 0.f;
#pragma unroll
        for (int q = 0; q < 8; q++) {
            float4 f = px[q];
            s2 += f.x * f.x + f.y * f.y + f.z * f.z + f.w * f.w;
            uc.h[4 * q + 0] = (_Float16)f.x;
            uc.h[4 * q + 1] = (_Float16)f.y;
            uc.h[4 * q + 2] = (_Float16)f.z;
            uc.h[4 * q + 3] = (_Float16)f.w;
        }
        half8* dst = (half8*)&xh[r * 32];
#pragma unroll
        for (int q = 0; q < 4; q++) dst[q] = uc.v[q];
        x2sL[r] = s2 * LOG2E;

        const float4* py = (const float4*)(yb + r * 32);
        float t2 = 0.f;
#pragma unroll
        for (int q = 0; q < 8; q++) {
            float4 f = py[q];
            t2 += f.x * f.x + f.y * f.y + f.z * f.z + f.w * f.w;
        }
        y2sL[r] = t2 * LOG2E;
    }
    if (tid < 16) rdy[tid] = 0;
    if (tid == 16) *prg = 0;
    __syncthreads();

    if (tid >= 64) {
        // ================= producer wave =================
        const int lane = tid - 64;
        const int qd = lane >> 4, xr = lane & 15;

        half8 yfrag[16];  // B-frags: lane holds y[ci*16+xr][qd*8+j]
        float yvL[16];
#pragma unroll
        for (int ci = 0; ci < 16; ci++) {
            const float* yp = yb + (ci * 16 + xr) * 32 + qd * 8;
            float4 f0 = *(const float4*)yp;
            float4 f1 = *(const float4*)(yp + 4);
            half8 v;
            v[0] = (_Float16)f0.x; v[1] = (_Float16)f0.y;
            v[2] = (_Float16)f0.z; v[3] = (_Float16)f0.w;
            v[4] = (_Float16)f1.x; v[5] = (_Float16)f1.y;
            v[6] = (_Float16)f1.z; v[7] = (_Float16)f1.w;
            yfrag[ci] = v;
            yvL[ci] = y2sL[ci * 16 + xr];
        }

        for (int sg = 0; sg < 16; sg++) {
            // ring-reuse gate: stripe sg touches drows [8sg, 8sg+70]; the
            // aliased drows (d-112) need consumer progress >= 8sg-40.
            if (sg >= 6) {
                const int need = 8 * sg - 40;
                while (*prg < need) {}
            }
            const half8 xf = *(const half8*)&xh[(sg * 16 + xr) * 32 + qd * 8];
            const float4 xl = *(const float4*)&x2sL[sg * 16 + qd * 4];
            const int p0 = 8 * sg + 2 * qd;  // global pair of acc[0],acc[1]
#pragma unroll
            for (int ci = 0; ci < 16; ci++) {
                f32x4 acc = {0.f, 0.f, 0.f, 0.f};
                acc = __builtin_amdgcn_mfma_f32_16x16x32_f16(xf, yfrag[ci], acc, 0, 0, 0);
                const int c = ci * 16 + xr;
                const float yv = yvL[ci];
                const float d0 = fmaxf(fmaf(M2L, acc[0], xl.x + yv), 0.f);
                const float d1 = fmaxf(fmaf(M2L, acc[1], xl.y + yv), 0.f);
                const float d2 = fmaxf(fmaf(M2L, acc[2], xl.z + yv), 0.f);
                const float d3 = fmaxf(fmaf(M2L, acc[3], xl.w + yv), 0.f);
                const half2_t h01 = pkrtz(d0, d1);
                const half2_t h23 = pkrtz(d2, d3);
                const int dr0 = p0 + (c >> 2);          // anti-diagonal row
                int s0_ = dr0;     if (s0_ >= RSLOT) s0_ -= RSLOT;
                int s1_ = dr0 + 1; if (s1_ >= RSLOT) s1_ -= RSLOT;
                *(half2_t*)&band[s0_ * DRB + 4 * c] = h01;
                *(half2_t*)&band[s1_ * DRB + 4 * c] = h23;
            }
            __threadfence_block();  // drain LDS writes before flagging
            if (lane == 0) rdy[sg] = 1;
        }
        return;
    }

    // ================= consumer (DP) wave =================
    const int lane = tid;
    // previous-B-row pairs (raw, no premerge) + prev diag-relay pair G0
    float pBM[4], pBS[4];
    pBM[0] = BIG; pBS[0] = 1.f;
    pBM[1] = BIG; pBS[1] = 1.f;
    pBM[2] = BIG; pBS[2] = 1.f;
    pBM[3] = BIG; pBS[3] = 1.f;
    float G0M = (lane == 0) ? 0.f : BIG, G0S = 1.f;
    float MpA3 = BIG, SpA3 = 1.f, MpB3 = BIG, SpB3 = 1.f;

    while (rdy[0] == 0) {}
    uint4 wreg = *(const uint4*)&band[16 * lane];  // drow 0

    auto step = [&](int s_) {
        // relays (DPP), independent
        const float MLA = shfl_up1(MpA3, BIG);
        const float MLB = shfl_up1(MpB3, BIG);
        const float SLA = shfl_up1(SpA3, 1.f);
        const float SLB = shfl_up1(SpB3, 1.f);

        // input masking: inactive lanes get huge, per-column-distinct d's
        const bool act = (unsigned)(s_ - lane - 1) < 128u;
        const unsigned wx = act ? wreg.x : MASKW0;
        const unsigned wy = act ? wreg.y : MASKW1;
        const unsigned wz = act ? wreg.z : MASKW2;
        const unsigned ww = act ? wreg.w : MASKW3;
        float dA[4], dB[4];
        dec2(wx, dA[0], dB[0]);
        dec2(wy, dA[1], dB[1]);
        dec2(wz, dA[2], dB[2]);
        dec2(ww, dA[3], dB[3]);

        // prefetch next drow (= s_), used next superstep — issued early
        int dn = (s_ > 190) ? 190 : s_;
        if (dn >= RSLOT) dn -= RSLOT;
        const uint4 wnext = *(const uint4*)&band[dn * DRB + 16 * lane];

        // A-row: cell k = 3way(up=pB[k], diag=(k?pB[k-1]:G0), left=chain)
        float MA[4], SA[4];
        cell3(pBM[0], pBS[0], G0M, G0S, MLA, SLA, dA[0], MA[0], SA[0]);
        cell3(pBM[1], pBS[1], pBM[0], pBS[0], MA[0], SA[0], dA[1], MA[1], SA[1]);
        cell3(pBM[2], pBS[2], pBM[1], pBS[1], MA[1], SA[1], dA[2], MA[2], SA[2]);
        cell3(pBM[3], pBS[3], pBM[2], pBS[2], MA[2], SA[2], dA[3], MA[3], SA[3]);

        // B-row: cell k = 3way(up=A[k], diag=(k?A[k-1]:MLA-relay), left=chain)
        float MB[4], SB[4];
        cell3(MA[0], SA[0], MLA, SLA, MLB, SLB, dB[0], MB[0], SB[0]);
        cell3(MA[1], SA[1], MA[0], SA[0], MB[0], SB[0], dB[1], MB[1], SB[1]);
        cell3(MA[2], SA[2], MA[1], SA[1], MB[1], SB[1], dB[2], MB[2], SB[2]);
        cell3(MA[3], SA[3], MA[2], SA[2], MB[2], SB[2], dB[3], MB[3], SB[3]);

        // UNCONDITIONAL commit (input masking makes inactive lanes no-ops)
        MpA3 = MA[3]; SpA3 = SA[3];
        MpB3 = MB[3]; SpB3 = SB[3];
#pragma unroll
        for (int k = 0; k < 4; k++) { pBM[k] = MB[k]; pBS[k] = SB[k]; }
        G0M = MLB; G0S = SLB;
        wreg = wnext;
    };

    // prologue: supersteps 1..7 (stripe 0 covers drows 0..7)
#pragma unroll
    for (int s_ = 1; s_ < 8; s_++) step(s_);

    // 23 groups of 8 supersteps, poll/publish hoisted to group head
    for (int g = 1; g < 24; g++) {
        int st = (g > 15) ? 15 : g;
        while (rdy[st] == 0) {}
        if (lane == 0) *prg = 8 * g;
        const int s0 = 8 * g;
#pragma unroll
        for (int k = 0; k < 8; k++) step(s0 + k);
    }

    // lane 63's superstep-191 commit is the final cell D[256][256]
    if (lane == 63)
        atomicAdd(out, (MpB3 - log2g(SpB3)) * (LN2 / 256.f));
}

extern "C" void kernel_launch(void* const* d_in, const int* in_sizes, int n_in,
                              void* d_out, int out_size, void* d_ws, size_t ws_size,
                              hipStream_t stream) {
    const float* x = (const float*)d_in[0];
    const float* y = (const float*)d_in[1];
    float* out = (float*)d_out;
    const int B = in_sizes[0] / (256 * 32);  // 256

    (void)hipFuncSetAttribute((const void*)sdtw_kernel,
                              hipFuncAttributeMaxDynamicSharedMemorySize,
                              LDS_BYTES);
    (void)hipMemsetAsync(d_out, 0, sizeof(float), stream);
    sdtw_kernel<<<dim3(B), dim3(128), LDS_BYTES, stream>>>(x, y, out);
}

// Round 8
// 118.681 us; speedup vs baseline: 1.1358x; 1.0194x over previous
//
#include <hip/hip_runtime.h>

#define BIG 1e8f
#define LN2 0.69314718f
#define LOG2E 1.44269504f
#define M2L -2.8853900818f  /* -2*log2(e) */

#define RSLOT 112           /* band ring slots (anti-diagonal rows); 8-divisible */
#define DRB 1040            /* drow stride bytes: 256 cols * 4B(half2) + 16 pad */

/* dynamic LDS layout */
#define OFF_XH   116480     /* band: [0, 116480) = 112*1040 */
#define OFF_X2S  132864     /* xh: 16384 B f16 */
#define OFF_Y2S  133888
#define OFF_RDY  134912     /* 16 ready flags */
#define OFF_PRG  134976     /* consumer progress */
#define LDS_BYTES 135040

typedef _Float16 half8 __attribute__((ext_vector_type(8)));
typedef _Float16 half2_t __attribute__((ext_vector_type(2)));
typedef float f32x4 __attribute__((ext_vector_type(4)));

__device__ __forceinline__ float exp2g(float x) {
#if __has_builtin(__builtin_amdgcn_exp2f)
    return __builtin_amdgcn_exp2f(x);
#else
    return exp2f(x);
#endif
}
__device__ __forceinline__ float log2g(float x) {
#if __has_builtin(__builtin_amdgcn_logf)
    return __builtin_amdgcn_logf(x);
#else
    return log2f(x);
#endif
}

__device__ __forceinline__ half2_t pkrtz(float a, float b) {
    return __builtin_bit_cast(half2_t, __builtin_amdgcn_cvt_pkrtz(a, b));
}

// whole-wave shift-up-by-1 via DPP wave_shr:1; lane 0 receives oldv.
__device__ __forceinline__ float shfl_up1(float v, float oldv) {
    int r = __builtin_amdgcn_update_dpp(
        __builtin_bit_cast(int, oldv), __builtin_bit_cast(int, v),
        0x138 /*wave_shr:1*/, 0xf, 0xf, false);
    return __builtin_bit_cast(float, r);
}

__device__ __forceinline__ void dec2(unsigned int w, float& a, float& b) {
    half2_t h = __builtin_bit_cast(half2_t, w);
    a = (float)h[0];
    b = (float)h[1];
}

// SELECTLESS 3-way softmin cell in exponential-pair form (v = M - log2(S)):
// out = d + softmin{up, diag, left}. mu = min3 -> one exponent is exactly 0
// (exp2(0)=1), the far ones flush to exact 0 -- no cmp/cndmask machinery.
__device__ __forceinline__ void cell3(float Mu, float Su, float Mg, float Sg,
                                      float Ml, float Sl, float dd,
                                      float& Mo, float& So) {
    const float mu = fminf(fminf(Mu, Mg), Ml);   // v_min3_f32
    const float eu = exp2g(mu - Mu);
    const float eg = exp2g(mu - Mg);
    const float el = exp2g(mu - Ml);
    So = fmaf(Su, eu, fmaf(Sg, eg, Sl * el));
    Mo = dd + mu;
}

// Inactive-lane word masks: per-column-DISTINCT huge f16 values (see R2).
#define MASKW0 0x7BFF7BFFu  /* 65504 */
#define MASKW1 0x70007000u  /* 8192  */
#define MASKW2 0x60006000u  /* 512   */
#define MASKW3 0x50005000u  /* 32    */

// One block = one batch, 2 waves on 2 SIMDs.
// Wave 1 (producer): MFMA dist staging into anti-diagonal LDS ring. Proven.
// Wave 0 (consumer): cell3 DP wavefront, software-pipelined: each step
//   fetches drow s (one ds_read at group-shared base + imm offset) and
//   decodes step s+1's masked inputs at its TAIL, so the next step opens
//   directly with DPP->A-chain. Steps whose decode target s+1 in [64,128]
//   skip masking entirely (all lanes active).
__global__ __launch_bounds__(128, 1) void sdtw_kernel(
    const float* __restrict__ x, const float* __restrict__ y,
    float* __restrict__ out) {
    extern __shared__ __align__(16) char smem[];
    unsigned char* band = (unsigned char*)smem;
    _Float16* xh = (_Float16*)(smem + OFF_XH);
    float* x2sL = (float*)(smem + OFF_X2S);   // row norms * log2(e)
    float* y2sL = (float*)(smem + OFF_Y2S);
    volatile int* rdy = (volatile int*)(smem + OFF_RDY);
    volatile int* prg = (volatile int*)(smem + OFF_PRG);

    const int tid = threadIdx.x;  // 0..127
    const int b = blockIdx.x;
    const float* xb = x + (size_t)b * 8192;
    const float* yb = y + (size_t)b * 8192;

    // ---- phase 0 (both waves): stage x as f16 + scaled norms; flags ----
#pragma unroll
    for (int rr = 0; rr < 2; rr++) {
        const int r = tid + rr * 128;
        const float4* px = (const float4*)(xb + r * 32);
        union { _Float16 h[32]; half8 v[4]; } uc;
        float s2 = 0.f;
#pragma unroll
        for (int q = 0; q < 8; q++) {
            float4 f = px[q];
            s2 += f.x * f.x + f.y * f.y + f.z * f.z + f.w * f.w;
            uc.h[4 * q + 0] = (_Float16)f.x;
            uc.h[4 * q + 1] = (_Float16)f.y;
            uc.h[4 * q + 2] = (_Float16)f.z;
            uc.h[4 * q + 3] = (_Float16)f.w;
        }
        half8* dst = (half8*)&xh[r * 32];
#pragma unroll
        for (int q = 0; q < 4; q++) dst[q] = uc.v[q];
        x2sL[r] = s2 * LOG2E;

        const float4* py = (const float4*)(yb + r * 32);
        float t2 = 0.f;
#pragma unroll
        for (int q = 0; q < 8; q++) {
            float4 f = py[q];
            t2 += f.x * f.x + f.y * f.y + f.z * f.z + f.w * f.w;
        }
        y2sL[r] = t2 * LOG2E;
    }
    if (tid < 16) rdy[tid] = 0;
    if (tid == 16) *prg = 0;
    __syncthreads();

    if (tid >= 64) {
        // ================= producer wave =================
        const int lane = tid - 64;
        const int qd = lane >> 4, xr = lane & 15;

        half8 yfrag[16];  // B-frags: lane holds y[ci*16+xr][qd*8+j]
        float yvL[16];
#pragma unroll
        for (int ci = 0; ci < 16; ci++) {
            const float* yp = yb + (ci * 16 + xr) * 32 + qd * 8;
            float4 f0 = *(const float4*)yp;
            float4 f1 = *(const float4*)(yp + 4);
            half8 v;
            v[0] = (_Float16)f0.x; v[1] = (_Float16)f0.y;
            v[2] = (_Float16)f0.z; v[3] = (_Float16)f0.w;
            v[4] = (_Float16)f1.x; v[5] = (_Float16)f1.y;
            v[6] = (_Float16)f1.z; v[7] = (_Float16)f1.w;
            yfrag[ci] = v;
            yvL[ci] = y2sL[ci * 16 + xr];
        }

        for (int sg = 0; sg < 16; sg++) {
            // ring-reuse gate: stripe sg touches drows [8sg, 8sg+70]; the
            // aliased drows (d-112) need consumer progress >= 8sg-40.
            if (sg >= 6) {
                const int need = 8 * sg - 40;
                while (*prg < need) {}
            }
            const half8 xf = *(const half8*)&xh[(sg * 16 + xr) * 32 + qd * 8];
            const float4 xl = *(const float4*)&x2sL[sg * 16 + qd * 4];
            const int p0 = 8 * sg + 2 * qd;  // global pair of acc[0],acc[1]
#pragma unroll
            for (int ci = 0; ci < 16; ci++) {
                f32x4 acc = {0.f, 0.f, 0.f, 0.f};
                acc = __builtin_amdgcn_mfma_f32_16x16x32_f16(xf, yfrag[ci], acc, 0, 0, 0);
                const int c = ci * 16 + xr;
                const float yv = yvL[ci];
                const float d0 = fmaxf(fmaf(M2L, acc[0], xl.x + yv), 0.f);
                const float d1 = fmaxf(fmaf(M2L, acc[1], xl.y + yv), 0.f);
                const float d2 = fmaxf(fmaf(M2L, acc[2], xl.z + yv), 0.f);
                const float d3 = fmaxf(fmaf(M2L, acc[3], xl.w + yv), 0.f);
                const half2_t h01 = pkrtz(d0, d1);
                const half2_t h23 = pkrtz(d2, d3);
                const int dr0 = p0 + (c >> 2);          // anti-diagonal row
                int s0_ = dr0;     if (s0_ >= RSLOT) s0_ -= RSLOT;
                int s1_ = dr0 + 1; if (s1_ >= RSLOT) s1_ -= RSLOT;
                *(half2_t*)&band[s0_ * DRB + 4 * c] = h01;
                *(half2_t*)&band[s1_ * DRB + 4 * c] = h23;
            }
            __threadfence_block();  // drain LDS writes before flagging
            if (lane == 0) rdy[sg] = 1;
        }
        return;
    }

    // ================= consumer (DP) wave =================
    const int lane = tid;
    // previous-B-row pairs (raw, no premerge) + prev diag-relay pair G0
    float pBM[4], pBS[4];
    pBM[0] = BIG; pBS[0] = 1.f;
    pBM[1] = BIG; pBS[1] = 1.f;
    pBM[2] = BIG; pBS[2] = 1.f;
    pBM[3] = BIG; pBS[3] = 1.f;
    float G0M = (lane == 0) ? 0.f : BIG, G0S = 1.f;
    float MpA3 = BIG, SpA3 = 1.f, MpB3 = BIG, SpB3 = 1.f;

    // current decoded inputs (for the upcoming step)
    float dAc[4], dBc[4];

    auto decode = [&](uint4 w, int s1, bool domask) {
        unsigned wx = w.x, wy = w.y, wz = w.z, ww = w.w;
        if (domask) {
            const bool act = (unsigned)(s1 - 1 - lane) < 128u;
            wx = act ? wx : MASKW0;
            wy = act ? wy : MASKW1;
            wz = act ? wz : MASKW2;
            ww = act ? ww : MASKW3;
        }
        dec2(wx, dAc[0], dBc[0]);
        dec2(wy, dAc[1], dBc[1]);
        dec2(wz, dAc[2], dBc[2]);
        dec2(ww, dAc[3], dBc[3]);
    };

    while (rdy[0] == 0) {}
    decode(*(const uint4*)&band[16 * lane], 1, true);  // drow 0 -> step 1

    // step s_: fetch drow s_ (inputs for step s_+1) from gb+koff, run cells
    // on current decoded inputs, then decode the fetched row (MASKD governs
    // the s_+1 activity mask; false only when s_+1 in [64,128]).
    auto step = [&](int s_, const char* gb, int koff, bool MASKD) {
        const float MLA = shfl_up1(MpA3, BIG);
        const float MLB = shfl_up1(MpB3, BIG);
        const float SLA = shfl_up1(SpA3, 1.f);
        const float SLB = shfl_up1(SpB3, 1.f);

        const uint4 wnext = *(const uint4*)(gb + koff);

        // A-row: cell k = 3way(up=pB[k], diag=(k?pB[k-1]:G0), left=chain)
        float MA[4], SA[4];
        cell3(pBM[0], pBS[0], G0M, G0S, MLA, SLA, dAc[0], MA[0], SA[0]);
        cell3(pBM[1], pBS[1], pBM[0], pBS[0], MA[0], SA[0], dAc[1], MA[1], SA[1]);
        cell3(pBM[2], pBS[2], pBM[1], pBS[1], MA[1], SA[1], dAc[2], MA[2], SA[2]);
        cell3(pBM[3], pBS[3], pBM[2], pBS[2], MA[2], SA[2], dAc[3], MA[3], SA[3]);

        // B-row: cell k = 3way(up=A[k], diag=(k?A[k-1]:MLA-relay), left=chain)
        float MB[4], SB[4];
        cell3(MA[0], SA[0], MLA, SLA, MLB, SLB, dBc[0], MB[0], SB[0]);
        cell3(MA[1], SA[1], MA[0], SA[0], MB[0], SB[0], dBc[1], MB[1], SB[1]);
        cell3(MA[2], SA[2], MA[1], SA[1], MB[1], SB[1], dBc[2], MB[2], SB[2]);
        cell3(MA[3], SA[3], MA[2], SA[2], MB[2], SB[2], dBc[3], MB[3], SB[3]);

        // decode next step's inputs at the tail (fills spine bubbles)
        decode(wnext, s_ + 1, MASKD);

        // UNCONDITIONAL commit (input masking makes inactive lanes no-ops)
        MpA3 = MA[3]; SpA3 = SA[3];
        MpB3 = MB[3]; SpB3 = SB[3];
#pragma unroll
        for (int k = 0; k < 4; k++) { pBM[k] = MB[k]; pBS[k] = SB[k]; }
        G0M = MLB; G0S = SLB;
    };

    // prologue: supersteps 1..7 (stripe 0 covers drows 0..7)
    {
        const char* gb0 = (const char*)&band[16 * lane];
#pragma unroll
        for (int s_ = 1; s_ < 8; s_++) step(s_, gb0, s_ * DRB, true);
    }

    // 23 groups of 8 supersteps; poll/publish at group head; group-shared
    // fetch base (RSLOT=112 is 8-divisible -> no wrap within a group).
    for (int g = 1; g < 24; g++) {
        int st = (g > 15) ? 15 : g;
        while (rdy[st] == 0) {}
        if (lane == 0) *prg = 8 * g;
        const int s0 = 8 * g;
        const int slot0 = (s0 >= RSLOT) ? s0 - RSLOT : s0;  // s0 <= 184 < 224
        const char* gb = (const char*)&band[slot0 * DRB + 16 * lane];
        if (g >= 8 && g <= 15) {
            // decode targets s_+1 in [65,128]: all lanes active, no masking
#pragma unroll
            for (int k = 0; k < 8; k++) step(s0 + k, gb, k * DRB, false);
        } else if (g < 23) {
#pragma unroll
            for (int k = 0; k < 8; k++) step(s0 + k, gb, k * DRB, true);
        } else {
            // g==23: steps 184..191; k==7 fetch (for step 192) is unused --
            // clamp its offset to drow 190's slot at compile time.
#pragma unroll
            for (int k = 0; k < 8; k++)
                step(s0 + k, gb, (k == 7 ? 6 : k) * DRB, true);
        }
    }

    // lane 63's superstep-191 commit is the final cell D[256][256]
    if (lane == 63)
        atomicAdd(out, (MpB3 - log2g(SpB3)) * (LN2 / 256.f));
}

extern "C" void kernel_launch(void* const* d_in, const int* in_sizes, int n_in,
                              void* d_out, int out_size, void* d_ws, size_t ws_size,
                              hipStream_t stream) {
    const float* x = (const float*)d_in[0];
    const float* y = (const float*)d_in[1];
    float* out = (float*)d_out;
    const int B = in_sizes[0] / (256 * 32);  // 256

    (void)hipFuncSetAttribute((const void*)sdtw_kernel,
                              hipFuncAttributeMaxDynamicSharedMemorySize,
                              LDS_BYTES);
    (void)hipMemsetAsync(d_out, 0, sizeof(float), stream);
    sdtw_kernel<<<dim3(B), dim3(128), LDS_BYTES, stream>>>(x, y, out);
}